// Round 18
// baseline (45.083 us; speedup 1.0000x reference)
//
#include <hip/hip_runtime.h>

#define BATCH 16384
#define N1 (BATCH * 196)
#define N2 (BATCH * 49)
#define S1 8      // samples per k1 block
#define NREC 80   // records per wave (16 waves): 1225 triu + 49 fc1 + 6 pad = 1280

// ws layout (bytes):
//   [0, 32768)            : partials1, 2048 x (sum,sumsq) doubles
//   [32768, 65536)        : partials2, 256 x (sum,sumsq) doubles (front)
//   [65536, 126976)       : wrec: 1280 records x 12 dwords (61440 B)
//   [262144, 6684672)     : l1g: bf16 gathered layout BATCH*196 ushort
//   [6684672, 10092544)   : l2g: BATCH*52 floats (stride-52 padded)
#define WS_P1_OFF    0
#define WS_P2_OFF    32768
#define WS_WREC_OFF  65536
#define WS_L1G_OFF   262144
#define WS_L2G_OFF   6684672

__device__ __forceinline__ unsigned short f2bf(float f) {
    unsigned u = __float_as_uint(f);
    unsigned r = (u + 0x7FFFu + ((u >> 16) & 1u)) >> 16;   // RTNE
    return (unsigned short)r;
}
__device__ __forceinline__ float bf2f(unsigned short h) {
    return __uint_as_float((unsigned)h << 16);
}
__device__ __forceinline__ float rfl_f(float v) {
    return __uint_as_float(__builtin_amdgcn_readfirstlane(__float_as_uint(v)));
}

// ---------------- k1: layer 1 (direct global loads, bf16 gathered out, partial stats) ----------------
__global__ void __launch_bounds__(256) k1(
        const float* __restrict__ x,
        const float* __restrict__ l1w1, const float* __restrict__ wA,
        const float* __restrict__ wB, const float* __restrict__ wC,
        const float* __restrict__ wD, const float* __restrict__ l1w3,
        const float* __restrict__ wf2, const float* __restrict__ wfc1,
        unsigned short* __restrict__ l1g, double* __restrict__ partials1,
        float* __restrict__ wrec) {
    __shared__ unsigned short ob[S1 * 196];   // 3136 B bf16 out buffer
    __shared__ float wls[4], wlss[4];
    int t = threadIdx.x;

    bool active = t < 196;
    int pos = active ? t : 0;
    int pi = pos / 14, pj = pos - 14 * pi;
    int r0 = (2 * pi) * 28 + 2 * pj;

    // self-prep fused weights for this thread's position (L2-resident inputs)
    float4 a0, a1, a2, a3;
    {
        float2 wt = *(const float2*)(l1w1 + r0);
        float2 wb = *(const float2*)(l1w1 + r0 + 28);
        a0 = make_float4(wt.x, wt.y, wb.x, wb.y);
        float mA0 = (pj != 0) ? 1.f : 0.f, mA1 = (pj != 13) ? 1.f : 0.f;
        float mB0 = (pi != 0) ? 1.f : 0.f, mB1 = (pi != 13) ? 1.f : 0.f;
        float eA[4] = {mA0, mA1, mA0, mA1};
        float eB[4] = {mB0, mB0, mB1, mB1};
        const int e1i[10] = {0,1,2,3,0,0,0,1,1,2};
        const int e2i[10] = {0,1,2,3,1,2,3,2,3,3};
        int wo = pi * 140 + 10 * pj;
        float wq[10];
        #pragma unroll
        for (int k = 0; k < 10; ++k) {
            float ca = eA[e1i[k]] * eA[e2i[k]];
            float cb = eB[e1i[k]] * eB[e2i[k]];
            wq[k] = wA[wo + k] * ca + wB[wo + k] * cb
                  + wC[wo + k] * ca * cb + wD[wo + k];
        }
        a1 = make_float4(wq[0], wq[1], wq[2], wq[3]);
        a2 = make_float4(wq[4], wq[5], wq[6], wq[7]);
        a3 = make_float4(wq[8], wq[9], l1w3[pos], 0.f);
    }

    // compute 8 samples directly from global (L1 coalesces; all lines fully reused in-block)
    const float* xb = x + (size_t)blockIdx.x * (S1 * 784) + r0;
    float accs[S1];
    float sum = 0.f, sumsq = 0.f;
    #pragma unroll
    for (int s = 0; s < S1; ++s) {
        float2 tp = *(const float2*)(xb + s * 784);
        float2 bo = *(const float2*)(xb + s * 784 + 28);
        float b00 = tp.x, b01 = tp.y, b10 = bo.x, b11 = bo.y;
        float acc = b00 * a0.x + b01 * a0.y + b10 * a0.z + b11 * a0.w;
        acc += b00 * b00 * a1.x + b01 * b01 * a1.y + b10 * b10 * a1.z + b11 * b11 * a1.w;
        acc += b00 * b01 * a2.x + b00 * b10 * a2.y + b00 * b11 * a2.z + b01 * b10 * a2.w;
        acc += b01 * b11 * a3.x + b10 * b11 * a3.y + a3.z;
        accs[s] = acc;
        if (active) { sum += acc; sumsq += acc * acc; }
    }

    // bf16 gathered-layout store via LDS transpose
    if (active) {
        int g = ((pi >> 1) * 7 + (pj >> 1)) * 4 + (pi & 1) * 2 + (pj & 1);
        #pragma unroll
        for (int s = 0; s < S1; ++s) ob[s * 196 + g] = f2bf(accs[s]);
    }
    __syncthreads();
    const unsigned int* ob32 = (const unsigned int*)ob;
    unsigned int* gout = (unsigned int*)(l1g + (size_t)blockIdx.x * (S1 * 196));
    #pragma unroll
    for (int r2 = 0; r2 < 3; ++r2) gout[t + 256 * r2] = ob32[t + 256 * r2];
    if (t < 16) gout[t + 768] = ob32[t + 768];

    // per-block stats -> unique slot (no atomics, no zero-init needed)
    #pragma unroll
    for (int off = 32; off; off >>= 1) {
        sum += __shfl_down(sum, off);
        sumsq += __shfl_down(sumsq, off);
    }
    int lane = t & 63, wid = t >> 6;
    if (lane == 0) { wls[wid] = sum; wlss[wid] = sumsq; }
    __syncthreads();
    if (t == 0) {
        partials1[blockIdx.x * 2]     = (double)(wls[0] + wls[1] + wls[2] + wls[3]);
        partials1[blockIdx.x * 2 + 1] = (double)(wlss[0] + wlss[1] + wlss[2] + wlss[3]);
    }

    // blocks 0..4: build the FC record stream: 16 waves x 80 records x
    // {10 weights, lds_off_p, lds_off_q}. Pair i -> wave i%16, slot i/16.
    if (blockIdx.x < 5) {
        int e = blockIdx.x * 256 + t;   // record id 0..1279
        if (e < 1280) {
            int w = e / NREC, j = e - w * NREC;
            int i = j * 16 + w;
            float wv[10];
            int ip = 0, iq = 0;
            if (i < 1225) {
                int rem = i, p = 0;
                while (rem >= 49 - p) { rem -= 49 - p; ++p; }
                int q = p + rem;
                #pragma unroll
                for (int o = 0; o < 10; ++o) wv[o] = wf2[o * 2401 + p * 49 + q];
                ip = p * 64; iq = q * 64;
            } else if (i < 1274) {
                int k = i - 1225;
                #pragma unroll
                for (int o = 0; o < 10; ++o) wv[o] = wfc1[o * 49 + k];
                ip = k * 64; iq = 49 * 64;   // row 49 == constant 1
            } else {
                #pragma unroll
                for (int o = 0; o < 10; ++o) wv[o] = 0.f;
            }
            float* r = wrec + (size_t)e * 12;
            #pragma unroll
            for (int o = 0; o < 10; ++o) r[o] = wv[o];
            ((int*)r)[10] = ip;
            ((int*)r)[11] = iq;
        }
    }
}

// ---------------- k2: layer 2 (reduce partials1, no LDS staging) ----------------
__global__ void __launch_bounds__(256) k2(
        const unsigned short* __restrict__ l1g,
        const float* __restrict__ l2w1, const float* __restrict__ l2w2,
        const float* __restrict__ l2w4,
        const float* __restrict__ gamma, const float* __restrict__ beta,
        const double* __restrict__ partials1, double* __restrict__ partials2,
        float* __restrict__ l2g) {
    __shared__ float wls[4], wlss[4];
    __shared__ double dred[8];
    __shared__ float bcast[2];
    int t = threadIdx.x;
    int lane = t & 63, wid = t >> 6;
    int sbase = blockIdx.x * S1;

    bool active = t < 196;
    int tt = active ? t : 0;
    int sub = tt / 49;
    int pos = tt - 49 * sub;

    // issue l1g loads early (latency hides under stats reduce)
    ushort4 u0 = *(const ushort4*)(l1g + ((size_t)(sbase + sub) * 196 + pos * 4));
    ushort4 u1 = *(const ushort4*)(l1g + ((size_t)(sbase + 4 + sub) * 196 + pos * 4));

    // reduce 2048 partials -> (a1, c1)
    {
        double s = 0.0, ss = 0.0;
        const double* p1 = partials1 + t * 16;
        #pragma unroll
        for (int k = 0; k < 8; ++k) { s += p1[k * 2]; ss += p1[k * 2 + 1]; }
        #pragma unroll
        for (int off = 32; off; off >>= 1) {
            s += __shfl_down(s, off);
            ss += __shfl_down(ss, off);
        }
        if (lane == 0) { dred[wid * 2] = s; dred[wid * 2 + 1] = ss; }
        __syncthreads();
        if (t == 0) {
            double S = dred[0] + dred[2] + dred[4] + dred[6];
            double SS = dred[1] + dred[3] + dred[5] + dred[7];
            double mean = S / (double)N1;
            double var = SS / (double)N1 - mean * mean;
            float a = (float)((double)gamma[0] / sqrt(var + 1e-5));
            bcast[0] = a;
            bcast[1] = beta[0] - (float)mean * a;
        }
    }

    // self-prep layer-2 per-position weights
    int pi = pos / 7, pj = pos - 7 * pi;
    int r0 = (2 * pi) * 14 + 2 * pj;
    float4 a0 = make_float4(l2w1[r0], l2w1[r0 + 1], l2w1[r0 + 14], l2w1[r0 + 15]);
    int wo = pi * 70 + 10 * pj;
    float4 q1 = make_float4(l2w2[wo],     l2w2[wo + 1], l2w2[wo + 2], l2w2[wo + 3]);
    float4 q2 = make_float4(l2w2[wo + 4], l2w2[wo + 5], l2w2[wo + 6], l2w2[wo + 7]);
    float4 q3 = make_float4(l2w2[wo + 8], l2w2[wo + 9], l2w4[pos], 0.f);
    __syncthreads();
    float a1 = bcast[0], c1 = bcast[1];

    float sum = 0.f, sumsq = 0.f;
    #pragma unroll
    for (int s2 = 0; s2 < 2; ++s2) {
        ushort4 u = s2 ? u1 : u0;
        int smp = sbase + s2 * 4 + sub;
        float h00 = fmaf(a1, bf2f(u.x), c1), h01 = fmaf(a1, bf2f(u.y), c1);
        float h10 = fmaf(a1, bf2f(u.z), c1), h11 = fmaf(a1, bf2f(u.w), c1);
        float acc = h00 * a0.x + h01 * a0.y + h10 * a0.z + h11 * a0.w;
        acc += h00 * h00 * q1.x + h01 * h01 * q1.y + h10 * h10 * q1.z + h11 * h11 * q1.w;
        acc += h00 * h01 * q2.x + h00 * h10 * q2.y + h00 * h11 * q2.z + h01 * h10 * q2.w;
        acc += h01 * h11 * q3.x + h10 * h11 * q3.y + q3.z;
        if (active) {
            l2g[(size_t)smp * 52 + pos] = acc;
            sum += acc;
            sumsq += acc * acc;
        }
    }

    #pragma unroll
    for (int off = 32; off; off >>= 1) {
        sum += __shfl_down(sum, off);
        sumsq += __shfl_down(sumsq, off);
    }
    if (lane == 0) { wls[wid] = sum; wlss[wid] = sumsq; }
    __syncthreads();
    if (t == 0) {
        partials2[blockIdx.x * 2]     = (double)(wls[0] + wls[1] + wls[2] + wls[3]);
        partials2[blockIdx.x * 2 + 1] = (double)(wlss[0] + wlss[1] + wlss[2] + wlss[3]);
    }
}

// ---------------- k3: FC via uniform record stream (data-driven triu) ----------------
__global__ void __launch_bounds__(1024) k3(
        const float* __restrict__ l2g, const float* __restrict__ wrec,
        const float* __restrict__ b_fc1, const float* __restrict__ b_fc2,
        const float* __restrict__ gamma, const float* __restrict__ beta,
        const double* __restrict__ partials2, float* __restrict__ out) {
    __shared__ float part[16][64][10];   // 40960 B
    __shared__ float vsm[50 * 64];       // 12800 B: BN'd v, [pos][sample], row 49 = 1.0
    __shared__ double dred[32];
    __shared__ float bcast[2];
    int t = threadIdx.x, lane = t & 63, wid = t >> 6;

    // load the block's 64 samples of l2g ONCE (coalesced float4)
    float4 val;
    int vs_s = 0, vs_k4 = 0;
    if (t < 832) {                       // 832 = 64 samples * 13 float4
        vs_s = t / 13;
        vs_k4 = t - vs_s * 13;
        val = ((const float4*)(l2g + (size_t)blockIdx.x * 64 * 52))[vs_s * 13 + vs_k4];
    }

    // reduce 2048 partials -> (a2, c2)
    {
        const double* p2 = partials2 + t * 4;
        double sd = p2[0] + p2[2], ssd = p2[1] + p2[3];
        #pragma unroll
        for (int off = 32; off; off >>= 1) {
            sd += __shfl_down(sd, off);
            ssd += __shfl_down(ssd, off);
        }
        if (lane == 0) { dred[wid * 2] = sd; dred[wid * 2 + 1] = ssd; }
        __syncthreads();
        if (t == 0) {
            double S = 0.0, SS = 0.0;
            #pragma unroll
            for (int w = 0; w < 16; ++w) { S += dred[w * 2]; SS += dred[w * 2 + 1]; }
            double mean = S / (double)N2;
            double var = SS / (double)N2 - mean * mean;
            float a = (float)((double)gamma[0] / sqrt(var + 1e-5));
            bcast[0] = a;
            bcast[1] = beta[0] - (float)mean * a;
        }
        __syncthreads();
    }
    float a2 = bcast[0], c2 = bcast[1];

    // scatter BN'd v into LDS [pos][sample]; row 49 = 1.0 (FC1 records)
    if (t < 832) {
        float vv[4] = {val.x, val.y, val.z, val.w};
        #pragma unroll
        for (int j = 0; j < 4; ++j) {
            int p = vs_k4 * 4 + j;
            if (p < 49) vsm[p * 64 + vs_s] = fmaf(a2, vv[j], c2);
        }
    }
    if (t < 64) vsm[49 * 64 + t] = 1.f;
    __syncthreads();

    // uniform record loop: all waves run identical code; indices come from data
    float acc[10];
    #pragma unroll
    for (int o = 0; o < 10; ++o) acc[o] = 0.f;

    int W = __builtin_amdgcn_readfirstlane(wid);
    const float* base = wrec + (size_t)W * NREC * 12;
    #pragma unroll 4
    for (int j = 0; j < NREC; ++j) {
        const float* rec = base + j * 12;
        int ip = __builtin_amdgcn_readfirstlane(((const int*)rec)[10]);
        int iq = __builtin_amdgcn_readfirstlane(((const int*)rec)[11]);
        float pv = vsm[ip + lane] * vsm[iq + lane];
        #pragma unroll
        for (int o = 0; o < 10; ++o) acc[o] = fmaf(pv, rfl_f(rec[o]), acc[o]);
    }

    #pragma unroll
    for (int o = 0; o < 10; ++o) part[wid][lane][o] = acc[o];
    __syncthreads();

    if (t < 640) {
        int sl = t / 10, o = t - 10 * sl;
        float r2 = 0.f;
        #pragma unroll
        for (int w = 0; w < 16; ++w) r2 += part[w][sl][o];
        out[(size_t)(blockIdx.x * 64 + sl) * 10 + o] = r2 + b_fc1[o] + b_fc2[o];
    }
}

extern "C" void kernel_launch(void* const* d_in, const int* in_sizes, int n_in,
                              void* d_out, int out_size, void* d_ws, size_t ws_size,
                              hipStream_t stream) {
    const float* x       = (const float*)d_in[0];
    const float* l1_w1   = (const float*)d_in[1];
    const float* l1_w2_1 = (const float*)d_in[2];
    const float* l1_w2_2 = (const float*)d_in[3];
    const float* l1_w2_3 = (const float*)d_in[4];
    const float* l1_w2_4 = (const float*)d_in[5];
    const float* l1_w3   = (const float*)d_in[6];
    const float* l2_w1   = (const float*)d_in[7];
    const float* l2_w2   = (const float*)d_in[8];
    const float* l2_w4   = (const float*)d_in[9];
    const float* w_fc1   = (const float*)d_in[10];
    const float* b_fc1   = (const float*)d_in[11];
    const float* w_fc2   = (const float*)d_in[12];
    const float* b_fc2   = (const float*)d_in[13];
    const float* bn_gamma = (const float*)d_in[14];
    const float* bn_beta  = (const float*)d_in[15];

    char* ws = (char*)d_ws;
    double* partials1 = (double*)(ws + WS_P1_OFF);
    double* partials2 = (double*)(ws + WS_P2_OFF);
    float* wrec = (float*)(ws + WS_WREC_OFF);
    unsigned short* l1g = (unsigned short*)(ws + WS_L1G_OFF);
    float* l2g = (float*)(ws + WS_L2G_OFF);
    float* out = (float*)d_out;

    k1<<<BATCH / S1, 256, 0, stream>>>(x, l1_w1, l1_w2_1, l1_w2_2, l1_w2_3, l1_w2_4,
                                       l1_w3, w_fc2, w_fc1, l1g, partials1, wrec);
    k2<<<BATCH / S1, 256, 0, stream>>>(l1g, l2_w1, l2_w2, l2_w4, bn_gamma, bn_beta,
                                       partials1, partials2, l2g);
    k3<<<BATCH / 64, 1024, 0, stream>>>(l2g, wrec, b_fc1, b_fc2,
                                        bn_gamma, bn_beta, partials2, out);
}

// Round 19
// 44.902 us; speedup vs baseline: 1.0040x; 1.0040x over previous
//
#include <hip/hip_runtime.h>

#define BATCH 16384
#define N1 (BATCH * 196)
#define N2 (BATCH * 49)
#define S1 8      // samples per k1 block
#define NREC 80   // records per wave (16 waves): 1225 triu + 49 fc1 + 6 pad = 1280

// ws layout (bytes):
//   [0, 32768)            : partials1, 2048 x (sum,sumsq) doubles
//   [32768, 65536)        : partials2, 256 x (sum,sumsq) doubles (front)
//   [65536, 126976)       : wrec: 1280 records x 12 dwords (61440 B)
//   [262144, 6684672)     : l1g: bf16 gathered layout BATCH*196 ushort
//   [6684672, 10092544)   : l2g: BATCH*52 floats (stride-52 padded)
#define WS_P1_OFF    0
#define WS_P2_OFF    32768
#define WS_WREC_OFF  65536
#define WS_L1G_OFF   262144
#define WS_L2G_OFF   6684672

__device__ __forceinline__ unsigned short f2bf(float f) {
    unsigned u = __float_as_uint(f);
    unsigned r = (u + 0x7FFFu + ((u >> 16) & 1u)) >> 16;   // RTNE
    return (unsigned short)r;
}
__device__ __forceinline__ float bf2f(unsigned short h) {
    return __uint_as_float((unsigned)h << 16);
}
__device__ __forceinline__ float rfl_f(float v) {
    return __uint_as_float(__builtin_amdgcn_readfirstlane(__float_as_uint(v)));
}

// ---------------- k1: layer 1 (direct global loads, bf16 gathered out, partial stats) ----------------
__global__ void __launch_bounds__(256) k1(
        const float* __restrict__ x,
        const float* __restrict__ l1w1, const float* __restrict__ wA,
        const float* __restrict__ wB, const float* __restrict__ wC,
        const float* __restrict__ wD, const float* __restrict__ l1w3,
        const float* __restrict__ wf2, const float* __restrict__ wfc1,
        unsigned short* __restrict__ l1g, double* __restrict__ partials1,
        float* __restrict__ wrec) {
    __shared__ unsigned short ob[S1 * 196];   // 3136 B bf16 out buffer
    __shared__ float wls[4], wlss[4];
    int t = threadIdx.x;

    bool active = t < 196;
    int pos = active ? t : 0;
    int pi = pos / 14, pj = pos - 14 * pi;
    int r0 = (2 * pi) * 28 + 2 * pj;

    // self-prep fused weights for this thread's position (L2-resident inputs)
    float4 a0, a1, a2, a3;
    {
        float2 wt = *(const float2*)(l1w1 + r0);
        float2 wb = *(const float2*)(l1w1 + r0 + 28);
        a0 = make_float4(wt.x, wt.y, wb.x, wb.y);
        float mA0 = (pj != 0) ? 1.f : 0.f, mA1 = (pj != 13) ? 1.f : 0.f;
        float mB0 = (pi != 0) ? 1.f : 0.f, mB1 = (pi != 13) ? 1.f : 0.f;
        float eA[4] = {mA0, mA1, mA0, mA1};
        float eB[4] = {mB0, mB0, mB1, mB1};
        const int e1i[10] = {0,1,2,3,0,0,0,1,1,2};
        const int e2i[10] = {0,1,2,3,1,2,3,2,3,3};
        int wo = pi * 140 + 10 * pj;
        float wq[10];
        #pragma unroll
        for (int k = 0; k < 10; ++k) {
            float ca = eA[e1i[k]] * eA[e2i[k]];
            float cb = eB[e1i[k]] * eB[e2i[k]];
            wq[k] = wA[wo + k] * ca + wB[wo + k] * cb
                  + wC[wo + k] * ca * cb + wD[wo + k];
        }
        a1 = make_float4(wq[0], wq[1], wq[2], wq[3]);
        a2 = make_float4(wq[4], wq[5], wq[6], wq[7]);
        a3 = make_float4(wq[8], wq[9], l1w3[pos], 0.f);
    }

    // compute 8 samples directly from global (L1 coalesces; all lines fully reused in-block)
    const float* xb = x + (size_t)blockIdx.x * (S1 * 784) + r0;
    float accs[S1];
    float sum = 0.f, sumsq = 0.f;
    #pragma unroll
    for (int s = 0; s < S1; ++s) {
        float2 tp = *(const float2*)(xb + s * 784);
        float2 bo = *(const float2*)(xb + s * 784 + 28);
        float b00 = tp.x, b01 = tp.y, b10 = bo.x, b11 = bo.y;
        float acc = b00 * a0.x + b01 * a0.y + b10 * a0.z + b11 * a0.w;
        acc += b00 * b00 * a1.x + b01 * b01 * a1.y + b10 * b10 * a1.z + b11 * b11 * a1.w;
        acc += b00 * b01 * a2.x + b00 * b10 * a2.y + b00 * b11 * a2.z + b01 * b10 * a2.w;
        acc += b01 * b11 * a3.x + b10 * b11 * a3.y + a3.z;
        accs[s] = acc;
        if (active) { sum += acc; sumsq += acc * acc; }
    }

    // bf16 gathered-layout store via LDS transpose
    if (active) {
        int g = ((pi >> 1) * 7 + (pj >> 1)) * 4 + (pi & 1) * 2 + (pj & 1);
        #pragma unroll
        for (int s = 0; s < S1; ++s) ob[s * 196 + g] = f2bf(accs[s]);
    }
    __syncthreads();
    const unsigned int* ob32 = (const unsigned int*)ob;
    unsigned int* gout = (unsigned int*)(l1g + (size_t)blockIdx.x * (S1 * 196));
    #pragma unroll
    for (int r2 = 0; r2 < 3; ++r2) gout[t + 256 * r2] = ob32[t + 256 * r2];
    if (t < 16) gout[t + 768] = ob32[t + 768];

    // per-block stats -> unique slot (no atomics, no zero-init needed)
    #pragma unroll
    for (int off = 32; off; off >>= 1) {
        sum += __shfl_down(sum, off);
        sumsq += __shfl_down(sumsq, off);
    }
    int lane = t & 63, wid = t >> 6;
    if (lane == 0) { wls[wid] = sum; wlss[wid] = sumsq; }
    __syncthreads();
    if (t == 0) {
        partials1[blockIdx.x * 2]     = (double)(wls[0] + wls[1] + wls[2] + wls[3]);
        partials1[blockIdx.x * 2 + 1] = (double)(wlss[0] + wlss[1] + wlss[2] + wlss[3]);
    }

    // blocks 0..4: build the FC record stream: 16 waves x 80 records x
    // {10 weights, lds_off_p, lds_off_q}. Pair i -> wave i%16, slot i/16.
    if (blockIdx.x < 5) {
        int e = blockIdx.x * 256 + t;   // record id 0..1279
        if (e < 1280) {
            int w = e / NREC, j = e - w * NREC;
            int i = j * 16 + w;
            float wv[10];
            int ip = 0, iq = 0;
            if (i < 1225) {
                int rem = i, p = 0;
                while (rem >= 49 - p) { rem -= 49 - p; ++p; }
                int q = p + rem;
                #pragma unroll
                for (int o = 0; o < 10; ++o) wv[o] = wf2[o * 2401 + p * 49 + q];
                ip = p * 64; iq = q * 64;
            } else if (i < 1274) {
                int k = i - 1225;
                #pragma unroll
                for (int o = 0; o < 10; ++o) wv[o] = wfc1[o * 49 + k];
                ip = k * 64; iq = 49 * 64;   // row 49 == constant 1
            } else {
                #pragma unroll
                for (int o = 0; o < 10; ++o) wv[o] = 0.f;
            }
            float* r = wrec + (size_t)e * 12;
            #pragma unroll
            for (int o = 0; o < 10; ++o) r[o] = wv[o];
            ((int*)r)[10] = ip;
            ((int*)r)[11] = iq;
        }
    }
}

// ---------------- k2: layer 2 (reduce partials1, no LDS staging) ----------------
__global__ void __launch_bounds__(256) k2(
        const unsigned short* __restrict__ l1g,
        const float* __restrict__ l2w1, const float* __restrict__ l2w2,
        const float* __restrict__ l2w4,
        const float* __restrict__ gamma, const float* __restrict__ beta,
        const double* __restrict__ partials1, double* __restrict__ partials2,
        float* __restrict__ l2g) {
    __shared__ float wls[4], wlss[4];
    __shared__ double dred[8];
    __shared__ float bcast[2];
    int t = threadIdx.x;
    int lane = t & 63, wid = t >> 6;
    int sbase = blockIdx.x * S1;

    bool active = t < 196;
    int tt = active ? t : 0;
    int sub = tt / 49;
    int pos = tt - 49 * sub;

    // issue l1g loads early (latency hides under stats reduce)
    ushort4 u0 = *(const ushort4*)(l1g + ((size_t)(sbase + sub) * 196 + pos * 4));
    ushort4 u1 = *(const ushort4*)(l1g + ((size_t)(sbase + 4 + sub) * 196 + pos * 4));

    // reduce 2048 partials -> (a1, c1)
    {
        double s = 0.0, ss = 0.0;
        const double* p1 = partials1 + t * 16;
        #pragma unroll
        for (int k = 0; k < 8; ++k) { s += p1[k * 2]; ss += p1[k * 2 + 1]; }
        #pragma unroll
        for (int off = 32; off; off >>= 1) {
            s += __shfl_down(s, off);
            ss += __shfl_down(ss, off);
        }
        if (lane == 0) { dred[wid * 2] = s; dred[wid * 2 + 1] = ss; }
        __syncthreads();
        if (t == 0) {
            double S = dred[0] + dred[2] + dred[4] + dred[6];
            double SS = dred[1] + dred[3] + dred[5] + dred[7];
            double mean = S / (double)N1;
            double var = SS / (double)N1 - mean * mean;
            float a = (float)((double)gamma[0] / sqrt(var + 1e-5));
            bcast[0] = a;
            bcast[1] = beta[0] - (float)mean * a;
        }
    }

    // self-prep layer-2 per-position weights
    int pi = pos / 7, pj = pos - 7 * pi;
    int r0 = (2 * pi) * 14 + 2 * pj;
    float4 a0 = make_float4(l2w1[r0], l2w1[r0 + 1], l2w1[r0 + 14], l2w1[r0 + 15]);
    int wo = pi * 70 + 10 * pj;
    float4 q1 = make_float4(l2w2[wo],     l2w2[wo + 1], l2w2[wo + 2], l2w2[wo + 3]);
    float4 q2 = make_float4(l2w2[wo + 4], l2w2[wo + 5], l2w2[wo + 6], l2w2[wo + 7]);
    float4 q3 = make_float4(l2w2[wo + 8], l2w2[wo + 9], l2w4[pos], 0.f);
    __syncthreads();
    float a1 = bcast[0], c1 = bcast[1];

    float sum = 0.f, sumsq = 0.f;
    #pragma unroll
    for (int s2 = 0; s2 < 2; ++s2) {
        ushort4 u = s2 ? u1 : u0;
        int smp = sbase + s2 * 4 + sub;
        float h00 = fmaf(a1, bf2f(u.x), c1), h01 = fmaf(a1, bf2f(u.y), c1);
        float h10 = fmaf(a1, bf2f(u.z), c1), h11 = fmaf(a1, bf2f(u.w), c1);
        float acc = h00 * a0.x + h01 * a0.y + h10 * a0.z + h11 * a0.w;
        acc += h00 * h00 * q1.x + h01 * h01 * q1.y + h10 * h10 * q1.z + h11 * h11 * q1.w;
        acc += h00 * h01 * q2.x + h00 * h10 * q2.y + h00 * h11 * q2.z + h01 * h10 * q2.w;
        acc += h01 * h11 * q3.x + h10 * h11 * q3.y + q3.z;
        if (active) {
            l2g[(size_t)smp * 52 + pos] = acc;
            sum += acc;
            sumsq += acc * acc;
        }
    }

    #pragma unroll
    for (int off = 32; off; off >>= 1) {
        sum += __shfl_down(sum, off);
        sumsq += __shfl_down(sumsq, off);
    }
    if (lane == 0) { wls[wid] = sum; wlss[wid] = sumsq; }
    __syncthreads();
    if (t == 0) {
        partials2[blockIdx.x * 2]     = (double)(wls[0] + wls[1] + wls[2] + wls[3]);
        partials2[blockIdx.x * 2 + 1] = (double)(wlss[0] + wlss[1] + wlss[2] + wlss[3]);
    }
}

// ---------------- k3: FC via uniform record stream (data-driven triu) ----------------
__global__ void __launch_bounds__(1024) k3(
        const float* __restrict__ l2g, const float* __restrict__ wrec,
        const float* __restrict__ b_fc1, const float* __restrict__ b_fc2,
        const float* __restrict__ gamma, const float* __restrict__ beta,
        const double* __restrict__ partials2, float* __restrict__ out) {
    __shared__ float part[16][64][10];   // 40960 B
    __shared__ float vsm[50 * 64];       // 12800 B: BN'd v, [pos][sample], row 49 = 1.0
    __shared__ double dred[32];
    __shared__ float bcast[2];
    int t = threadIdx.x, lane = t & 63, wid = t >> 6;

    // load the block's 64 samples of l2g ONCE (coalesced float4)
    float4 val;
    int vs_s = 0, vs_k4 = 0;
    if (t < 832) {                       // 832 = 64 samples * 13 float4
        vs_s = t / 13;
        vs_k4 = t - vs_s * 13;
        val = ((const float4*)(l2g + (size_t)blockIdx.x * 64 * 52))[vs_s * 13 + vs_k4];
    }

    // reduce 2048 partials -> (a2, c2)
    {
        const double* p2 = partials2 + t * 4;
        double sd = p2[0] + p2[2], ssd = p2[1] + p2[3];
        #pragma unroll
        for (int off = 32; off; off >>= 1) {
            sd += __shfl_down(sd, off);
            ssd += __shfl_down(ssd, off);
        }
        if (lane == 0) { dred[wid * 2] = sd; dred[wid * 2 + 1] = ssd; }
        __syncthreads();
        if (t == 0) {
            double S = 0.0, SS = 0.0;
            #pragma unroll
            for (int w = 0; w < 16; ++w) { S += dred[w * 2]; SS += dred[w * 2 + 1]; }
            double mean = S / (double)N2;
            double var = SS / (double)N2 - mean * mean;
            float a = (float)((double)gamma[0] / sqrt(var + 1e-5));
            bcast[0] = a;
            bcast[1] = beta[0] - (float)mean * a;
        }
        __syncthreads();
    }
    float a2 = bcast[0], c2 = bcast[1];

    // scatter BN'd v into LDS [pos][sample]; row 49 = 1.0 (FC1 records)
    if (t < 832) {
        float vv[4] = {val.x, val.y, val.z, val.w};
        #pragma unroll
        for (int j = 0; j < 4; ++j) {
            int p = vs_k4 * 4 + j;
            if (p < 49) vsm[p * 64 + vs_s] = fmaf(a2, vv[j], c2);
        }
    }
    if (t < 64) vsm[49 * 64 + t] = 1.f;
    __syncthreads();

    // uniform record loop: all waves run identical code; indices come from data
    float acc[10];
    #pragma unroll
    for (int o = 0; o < 10; ++o) acc[o] = 0.f;

    int W = __builtin_amdgcn_readfirstlane(wid);
    const float* base = wrec + (size_t)W * NREC * 12;
    #pragma unroll 4
    for (int j = 0; j < NREC; ++j) {
        const float* rec = base + j * 12;
        int ip = __builtin_amdgcn_readfirstlane(((const int*)rec)[10]);
        int iq = __builtin_amdgcn_readfirstlane(((const int*)rec)[11]);
        float pv = vsm[ip + lane] * vsm[iq + lane];
        #pragma unroll
        for (int o = 0; o < 10; ++o) acc[o] = fmaf(pv, rfl_f(rec[o]), acc[o]);
    }

    #pragma unroll
    for (int o = 0; o < 10; ++o) part[wid][lane][o] = acc[o];
    __syncthreads();

    if (t < 640) {
        int sl = t / 10, o = t - 10 * sl;
        float r2 = 0.f;
        #pragma unroll
        for (int w = 0; w < 16; ++w) r2 += part[w][sl][o];
        out[(size_t)(blockIdx.x * 64 + sl) * 10 + o] = r2 + b_fc1[o] + b_fc2[o];
    }
}

extern "C" void kernel_launch(void* const* d_in, const int* in_sizes, int n_in,
                              void* d_out, int out_size, void* d_ws, size_t ws_size,
                              hipStream_t stream) {
    const float* x       = (const float*)d_in[0];
    const float* l1_w1   = (const float*)d_in[1];
    const float* l1_w2_1 = (const float*)d_in[2];
    const float* l1_w2_2 = (const float*)d_in[3];
    const float* l1_w2_3 = (const float*)d_in[4];
    const float* l1_w2_4 = (const float*)d_in[5];
    const float* l1_w3   = (const float*)d_in[6];
    const float* l2_w1   = (const float*)d_in[7];
    const float* l2_w2   = (const float*)d_in[8];
    const float* l2_w4   = (const float*)d_in[9];
    const float* w_fc1   = (const float*)d_in[10];
    const float* b_fc1   = (const float*)d_in[11];
    const float* w_fc2   = (const float*)d_in[12];
    const float* b_fc2   = (const float*)d_in[13];
    const float* bn_gamma = (const float*)d_in[14];
    const float* bn_beta  = (const float*)d_in[15];

    char* ws = (char*)d_ws;
    double* partials1 = (double*)(ws + WS_P1_OFF);
    double* partials2 = (double*)(ws + WS_P2_OFF);
    float* wrec = (float*)(ws + WS_WREC_OFF);
    unsigned short* l1g = (unsigned short*)(ws + WS_L1G_OFF);
    float* l2g = (float*)(ws + WS_L2G_OFF);
    float* out = (float*)d_out;

    k1<<<BATCH / S1, 256, 0, stream>>>(x, l1_w1, l1_w2_1, l1_w2_2, l1_w2_3, l1_w2_4,
                                       l1_w3, w_fc2, w_fc1, l1g, partials1, wrec);
    k2<<<BATCH / S1, 256, 0, stream>>>(l1g, l2_w1, l2_w2, l2_w4, bn_gamma, bn_beta,
                                       partials1, partials2, l2g);
    k3<<<BATCH / 64, 1024, 0, stream>>>(l2g, wrec, b_fc1, b_fc2,
                                        bn_gamma, bn_beta, partials2, out);
}

// Round 20
// 38.824 us; speedup vs baseline: 1.1612x; 1.1566x over previous
//
#include <hip/hip_runtime.h>

#define BATCH 16384
#define N1 (BATCH * 196)
#define N2 (BATCH * 49)
#define S1 8      // samples per k1 block
#define NREC 80   // records per wave (16 waves): 1225 triu + 49 fc1 + 6 pad = 1280

// ws layout (bytes):
//   [0, 32768)            : partials1, 2048 x (sum,sumsq) doubles
//   [32768, 36864)        : partials2, 256 x (sum,sumsq) doubles
//   [65536, 126976)       : wrec: 1280 records x 12 dwords (61440 B)
//   [262144, 6684672)     : l1g: bf16 gathered layout BATCH*196 ushort
//   [6684672, 10092544)   : l2g: BATCH*52 floats (stride-52 padded)
#define WS_P1_OFF    0
#define WS_P2_OFF    32768
#define WS_WREC_OFF  65536
#define WS_L1G_OFF   262144
#define WS_L2G_OFF   6684672

__device__ __forceinline__ unsigned short f2bf(float f) {
    unsigned u = __float_as_uint(f);
    unsigned r = (u + 0x7FFFu + ((u >> 16) & 1u)) >> 16;   // RTNE
    return (unsigned short)r;
}
__device__ __forceinline__ float bf2f(unsigned short h) {
    return __uint_as_float((unsigned)h << 16);
}
__device__ __forceinline__ float rfl_f(float v) {
    return __uint_as_float(__builtin_amdgcn_readfirstlane(__float_as_uint(v)));
}

// ---------------- k1: layer 1 (LDS-staged, self-prep weights, bf16 gathered out) ----------------
__global__ void __launch_bounds__(256) k1(
        const float* __restrict__ x,
        const float* __restrict__ l1w1, const float* __restrict__ wA,
        const float* __restrict__ wB, const float* __restrict__ wC,
        const float* __restrict__ wD, const float* __restrict__ l1w3,
        const float* __restrict__ wf2, const float* __restrict__ wfc1,
        unsigned short* __restrict__ l1g, double* __restrict__ partials1,
        float* __restrict__ wrec) {
    __shared__ __align__(16) float xs[S1 * 784];   // 25088 B; reused as bf16 out buffer
    __shared__ float wls[4], wlss[4];
    int t = threadIdx.x;

    // stage x tile: issue global loads first
    const float4* src = (const float4*)(x + (size_t)blockIdx.x * (S1 * 784));
    float4 rbuf[6];
    #pragma unroll
    for (int i = 0; i < 6; ++i) rbuf[i] = src[t + 256 * i];
    float4 rtail;
    if (t < 32) rtail = src[t + 1536];

    // self-prep fused weights for this thread's position (L2-resident inputs)
    bool active = t < 196;
    int pos = active ? t : 0;
    int pi = pos / 14, pj = pos - 14 * pi;
    int r0 = (2 * pi) * 28 + 2 * pj;
    float4 a0, a1, a2, a3;
    {
        float2 wt = *(const float2*)(l1w1 + r0);
        float2 wb = *(const float2*)(l1w1 + r0 + 28);
        a0 = make_float4(wt.x, wt.y, wb.x, wb.y);
        float mA0 = (pj != 0) ? 1.f : 0.f, mA1 = (pj != 13) ? 1.f : 0.f;
        float mB0 = (pi != 0) ? 1.f : 0.f, mB1 = (pi != 13) ? 1.f : 0.f;
        float eA[4] = {mA0, mA1, mA0, mA1};
        float eB[4] = {mB0, mB0, mB1, mB1};
        const int e1i[10] = {0,1,2,3,0,0,0,1,1,2};
        const int e2i[10] = {0,1,2,3,1,2,3,2,3,3};
        int wo = pi * 140 + 10 * pj;
        float wq[10];
        #pragma unroll
        for (int k = 0; k < 10; ++k) {
            float ca = eA[e1i[k]] * eA[e2i[k]];
            float cb = eB[e1i[k]] * eB[e2i[k]];
            wq[k] = wA[wo + k] * ca + wB[wo + k] * cb
                  + wC[wo + k] * ca * cb + wD[wo + k];
        }
        a1 = make_float4(wq[0], wq[1], wq[2], wq[3]);
        a2 = make_float4(wq[4], wq[5], wq[6], wq[7]);
        a3 = make_float4(wq[8], wq[9], l1w3[pos], 0.f);
    }

    float4* dst = (float4*)xs;
    #pragma unroll
    for (int i = 0; i < 6; ++i) dst[t + 256 * i] = rbuf[i];
    if (t < 32) dst[t + 1536] = rtail;
    __syncthreads();

    float accs[S1];
    float sum = 0.f, sumsq = 0.f;
    #pragma unroll
    for (int s = 0; s < S1; ++s) {
        const float* xb = xs + s * 784;
        float2 tp = *(const float2*)(xb + r0);
        float2 bo = *(const float2*)(xb + r0 + 28);
        float b00 = tp.x, b01 = tp.y, b10 = bo.x, b11 = bo.y;
        float acc = b00 * a0.x + b01 * a0.y + b10 * a0.z + b11 * a0.w;
        acc += b00 * b00 * a1.x + b01 * b01 * a1.y + b10 * b10 * a1.z + b11 * b11 * a1.w;
        acc += b00 * b01 * a2.x + b00 * b10 * a2.y + b00 * b11 * a2.z + b01 * b10 * a2.w;
        acc += b01 * b11 * a3.x + b10 * b11 * a3.y + a3.z;
        accs[s] = acc;
        if (active) { sum += acc; sumsq += acc * acc; }
    }

    // bf16 gathered-layout store via LDS transpose (xs reused)
    __syncthreads();
    unsigned short* ob = (unsigned short*)xs;
    if (active) {
        int g = ((pi >> 1) * 7 + (pj >> 1)) * 4 + (pi & 1) * 2 + (pj & 1);
        #pragma unroll
        for (int s = 0; s < S1; ++s) ob[s * 196 + g] = f2bf(accs[s]);
    }
    __syncthreads();
    const unsigned int* ob32 = (const unsigned int*)ob;
    unsigned int* gout = (unsigned int*)(l1g + (size_t)blockIdx.x * (S1 * 196));
    #pragma unroll
    for (int r2 = 0; r2 < 3; ++r2) gout[t + 256 * r2] = ob32[t + 256 * r2];
    if (t < 16) gout[t + 768] = ob32[t + 768];

    // per-block stats -> unique slot (no atomics, no zero-init needed)
    #pragma unroll
    for (int off = 32; off; off >>= 1) {
        sum += __shfl_down(sum, off);
        sumsq += __shfl_down(sumsq, off);
    }
    int lane = t & 63, wid = t >> 6;
    if (lane == 0) { wls[wid] = sum; wlss[wid] = sumsq; }
    __syncthreads();
    if (t == 0) {
        partials1[blockIdx.x * 2]     = (double)(wls[0] + wls[1] + wls[2] + wls[3]);
        partials1[blockIdx.x * 2 + 1] = (double)(wlss[0] + wlss[1] + wlss[2] + wlss[3]);
    }

    // blocks 0..4: build the FC record stream: 16 waves x 80 records x
    // {10 weights, lds_off_p, lds_off_q}. Pair i -> wave i%16, slot i/16.
    if (blockIdx.x < 5) {
        int e = blockIdx.x * 256 + t;   // record id 0..1279
        if (e < 1280) {
            int w = e / NREC, j = e - w * NREC;
            int i = j * 16 + w;
            float wv[10];
            int ip = 0, iq = 0;
            if (i < 1225) {
                int rem = i, p = 0;
                while (rem >= 49 - p) { rem -= 49 - p; ++p; }
                int q = p + rem;
                #pragma unroll
                for (int o = 0; o < 10; ++o) wv[o] = wf2[o * 2401 + p * 49 + q];
                ip = p * 64; iq = q * 64;
            } else if (i < 1274) {
                int k = i - 1225;
                #pragma unroll
                for (int o = 0; o < 10; ++o) wv[o] = wfc1[o * 49 + k];
                ip = k * 64; iq = 49 * 64;   // row 49 == constant 1
            } else {
                #pragma unroll
                for (int o = 0; o < 10; ++o) wv[o] = 0.f;
            }
            float* r = wrec + (size_t)e * 12;
            #pragma unroll
            for (int o = 0; o < 10; ++o) r[o] = wv[o];
            ((int*)r)[10] = ip;
            ((int*)r)[11] = iq;
        }
    }
}

// ---------------- k2: layer 2, 256 fat blocks (64 samples), partials1 re-read 8 MB not 64 MB ----------------
__global__ void __launch_bounds__(1024) k2(
        const unsigned short* __restrict__ l1g,
        const float* __restrict__ l2w1, const float* __restrict__ l2w2,
        const float* __restrict__ l2w4,
        const float* __restrict__ gamma, const float* __restrict__ beta,
        const double* __restrict__ partials1, double* __restrict__ partials2,
        float* __restrict__ l2g) {
    __shared__ float wkv[49 * 16];
    __shared__ double dred[32];
    __shared__ float wls[16], wlss[16];
    __shared__ float bcast[2];
    int t = threadIdx.x, lane = t & 63, wid = t >> 6;
    int sbase = blockIdx.x * 64;

    // stage per-pos layer2 weights
    if (t < 49) {
        int pos = t, pi = pos / 7, pj = pos - 7 * pi;
        int r0 = 2 * pi * 14 + 2 * pj, wo = pi * 70 + 10 * pj;
        float* w = wkv + pos * 16;
        w[0] = l2w1[r0];      w[1] = l2w1[r0 + 1];
        w[2] = l2w1[r0 + 14]; w[3] = l2w1[r0 + 15];
        #pragma unroll
        for (int k = 0; k < 10; ++k) w[4 + k] = l2w2[wo + k];
        w[14] = l2w4[pos];
    }

    // reduce partials1 (2048 slots = 4096 doubles over 1024 threads) -> (a1, c1)
    {
        const double* p1 = partials1 + (size_t)t * 4;
        double sd = p1[0] + p1[2];
        double ssd = p1[1] + p1[3];
        #pragma unroll
        for (int off = 32; off; off >>= 1) {
            sd += __shfl_down(sd, off);
            ssd += __shfl_down(ssd, off);
        }
        if (lane == 0) { dred[wid * 2] = sd; dred[wid * 2 + 1] = ssd; }
        __syncthreads();
        if (t == 0) {
            double S = 0.0, SS = 0.0;
            #pragma unroll
            for (int w = 0; w < 16; ++w) { S += dred[w * 2]; SS += dred[w * 2 + 1]; }
            double mean = S / (double)N1;
            double var  = SS / (double)N1 - mean * mean;
            float a = (float)((double)gamma[0] / sqrt(var + 1e-5));
            bcast[0] = a;
            bcast[1] = beta[0] - (float)mean * a;
        }
        __syncthreads();
    }
    float a1 = bcast[0], c1 = bcast[1];

    // compute layer2 for 64 samples x 49 pos (coalesced ushort4 loads), write l2g
    float psum = 0.f, psq = 0.f;
    #pragma unroll
    for (int i = 0; i < 4; ++i) {
        int idx = i * 1024 + t;
        if (idx < 3136) {
            int s = idx / 49, pos = idx - s * 49;
            ushort4 u = *(const ushort4*)(l1g + ((size_t)(sbase + s) * 196 + pos * 4));
            const float* w = wkv + pos * 16;
            float h00 = fmaf(a1, bf2f(u.x), c1);
            float h01 = fmaf(a1, bf2f(u.y), c1);
            float h10 = fmaf(a1, bf2f(u.z), c1);
            float h11 = fmaf(a1, bf2f(u.w), c1);
            float acc = h00 * w[0] + h01 * w[1] + h10 * w[2] + h11 * w[3];
            acc += h00 * h00 * w[4] + h01 * h01 * w[5] + h10 * h10 * w[6] + h11 * h11 * w[7];
            acc += h00 * h01 * w[8] + h00 * h10 * w[9] + h00 * h11 * w[10] + h01 * h10 * w[11];
            acc += h01 * h11 * w[12] + h10 * h11 * w[13] + w[14];
            l2g[(size_t)(sbase + s) * 52 + pos] = acc;
            psum += acc;
            psq += acc * acc;
        }
    }
    #pragma unroll
    for (int off = 32; off; off >>= 1) {
        psum += __shfl_down(psum, off);
        psq  += __shfl_down(psq, off);
    }
    if (lane == 0) { wls[wid] = psum; wlss[wid] = psq; }
    __syncthreads();
    if (t == 0) {
        float S = 0.f, SS = 0.f;
        #pragma unroll
        for (int w = 0; w < 16; ++w) { S += wls[w]; SS += wlss[w]; }
        partials2[blockIdx.x * 2]     = (double)S;
        partials2[blockIdx.x * 2 + 1] = (double)SS;
    }
}

// ---------------- k3: FC via uniform record stream (data-driven triu) ----------------
__global__ void __launch_bounds__(1024) k3(
        const float* __restrict__ l2g, const float* __restrict__ wrec,
        const float* __restrict__ b_fc1, const float* __restrict__ b_fc2,
        const float* __restrict__ gamma, const float* __restrict__ beta,
        const double* __restrict__ partials2, float* __restrict__ out) {
    __shared__ float part[16][64][10];   // 40960 B
    __shared__ float vsm[50 * 64];       // 12800 B: BN'd v, [pos][sample], row 49 = 1.0
    __shared__ double dred[32];
    __shared__ float bcast[2];
    int t = threadIdx.x, lane = t & 63, wid = t >> 6;

    // load the block's 64 samples of l2g ONCE (coalesced float4)
    float4 val;
    int vs_s = 0, vs_k4 = 0;
    if (t < 832) {                       // 832 = 64 samples * 13 float4
        vs_s = t / 13;
        vs_k4 = t - vs_s * 13;
        val = ((const float4*)(l2g + (size_t)blockIdx.x * 64 * 52))[vs_s * 13 + vs_k4];
    }

    // reduce 256 partials -> (a2, c2)
    {
        double sd = 0.0, ssd = 0.0;
        if (t < 256) {
            sd = partials2[(size_t)t * 2];
            ssd = partials2[(size_t)t * 2 + 1];
        }
        #pragma unroll
        for (int off = 32; off; off >>= 1) {
            sd += __shfl_down(sd, off);
            ssd += __shfl_down(ssd, off);
        }
        if (lane == 0) { dred[wid * 2] = sd; dred[wid * 2 + 1] = ssd; }
        __syncthreads();
        if (t == 0) {
            double S = 0.0, SS = 0.0;
            #pragma unroll
            for (int w = 0; w < 4; ++w) { S += dred[w * 2]; SS += dred[w * 2 + 1]; }
            double mean = S / (double)N2;
            double var = SS / (double)N2 - mean * mean;
            float a = (float)((double)gamma[0] / sqrt(var + 1e-5));
            bcast[0] = a;
            bcast[1] = beta[0] - (float)mean * a;
        }
        __syncthreads();
    }
    float a2 = bcast[0], c2 = bcast[1];

    // scatter BN'd v into LDS [pos][sample]; row 49 = 1.0 (FC1 records)
    if (t < 832) {
        float vv[4] = {val.x, val.y, val.z, val.w};
        #pragma unroll
        for (int j = 0; j < 4; ++j) {
            int p = vs_k4 * 4 + j;
            if (p < 49) vsm[p * 64 + vs_s] = fmaf(a2, vv[j], c2);
        }
    }
    if (t < 64) vsm[49 * 64 + t] = 1.f;
    __syncthreads();

    // uniform record loop: all waves run identical code; indices come from data
    float acc[10];
    #pragma unroll
    for (int o = 0; o < 10; ++o) acc[o] = 0.f;

    int W = __builtin_amdgcn_readfirstlane(wid);
    const float* base = wrec + (size_t)W * NREC * 12;
    #pragma unroll 4
    for (int j = 0; j < NREC; ++j) {
        const float* rec = base + j * 12;
        int ip = __builtin_amdgcn_readfirstlane(((const int*)rec)[10]);
        int iq = __builtin_amdgcn_readfirstlane(((const int*)rec)[11]);
        float pv = vsm[ip + lane] * vsm[iq + lane];
        #pragma unroll
        for (int o = 0; o < 10; ++o) acc[o] = fmaf(pv, rfl_f(rec[o]), acc[o]);
    }

    #pragma unroll
    for (int o = 0; o < 10; ++o) part[wid][lane][o] = acc[o];
    __syncthreads();

    if (t < 640) {
        int sl = t / 10, o = t - 10 * sl;
        float r2 = 0.f;
        #pragma unroll
        for (int w = 0; w < 16; ++w) r2 += part[w][sl][o];
        out[(size_t)(blockIdx.x * 64 + sl) * 10 + o] = r2 + b_fc1[o] + b_fc2[o];
    }
}

extern "C" void kernel_launch(void* const* d_in, const int* in_sizes, int n_in,
                              void* d_out, int out_size, void* d_ws, size_t ws_size,
                              hipStream_t stream) {
    const float* x       = (const float*)d_in[0];
    const float* l1_w1   = (const float*)d_in[1];
    const float* l1_w2_1 = (const float*)d_in[2];
    const float* l1_w2_2 = (const float*)d_in[3];
    const float* l1_w2_3 = (const float*)d_in[4];
    const float* l1_w2_4 = (const float*)d_in[5];
    const float* l1_w3   = (const float*)d_in[6];
    const float* l2_w1   = (const float*)d_in[7];
    const float* l2_w2   = (const float*)d_in[8];
    const float* l2_w4   = (const float*)d_in[9];
    const float* w_fc1   = (const float*)d_in[10];
    const float* b_fc1   = (const float*)d_in[11];
    const float* w_fc2   = (const float*)d_in[12];
    const float* b_fc2   = (const float*)d_in[13];
    const float* bn_gamma = (const float*)d_in[14];
    const float* bn_beta  = (const float*)d_in[15];

    char* ws = (char*)d_ws;
    double* partials1 = (double*)(ws + WS_P1_OFF);
    double* partials2 = (double*)(ws + WS_P2_OFF);
    float* wrec = (float*)(ws + WS_WREC_OFF);
    unsigned short* l1g = (unsigned short*)(ws + WS_L1G_OFF);
    float* l2g = (float*)(ws + WS_L2G_OFF);
    float* out = (float*)d_out;

    k1<<<BATCH / S1, 256, 0, stream>>>(x, l1_w1, l1_w2_1, l1_w2_2, l1_w2_3, l1_w2_4,
                                       l1_w3, w_fc2, w_fc1, l1g, partials1, wrec);
    k2<<<BATCH / 64, 1024, 0, stream>>>(l1g, l2_w1, l2_w2, l2_w4, bn_gamma, bn_beta,
                                        partials1, partials2, l2g);
    k3<<<BATCH / 64, 1024, 0, stream>>>(l2g, wrec, b_fc1, b_fc2,
                                        bn_gamma, bn_beta, partials2, out);
}